// Round 1
// baseline (19113.112 us; speedup 1.0000x reference)
//
#include <hip/hip_runtime.h>
#include <stdint.h>

// ---------------------------------------------------------------------------
// Bidirectional 3-layer LSTM encoder, B=32 T=2048 U=256 H4=1024.
//
// Architecture:
//  - prep kernels: repack recurrent U weights into per-lane MFMA B-fragment
//    order (bf16), transpose input-projection W into B^T panels (bf16).
//  - xz_gemm: per layer 1..2, per 256-step chunk, computes xz = x@W + bias
//    for both directions (128x128-tile MFMA, m97-style global_load_lds).
//  - rec_step: the recurrence. 16 WGs = 2 dirs x 8 column-slices; each WG
//    owns 32 units x all 32 batch. Weights VGPR-resident. Per step:
//    spin on flags -> stage h (global_load_lds, fragment-order, linear) ->
//    MFMA 32x32x16 -> z to LDS -> gates (fp32 c in regs) -> publish h
//    (agent-scope write-through) -> flag++.
// ---------------------------------------------------------------------------

typedef unsigned short u16;
typedef unsigned int   u32;
typedef unsigned long long u64;
typedef __attribute__((ext_vector_type(8)))  short short8;   // 8 x bf16 (4 VGPR)
typedef __attribute__((ext_vector_type(16))) float f32x16;

#define B_   32
#define T_   2048
#define U_   256
#define H4_  1024
#define CHUNK 256
#define FLAG_STRIDE 16   // u32s per flag slot (64B, avoid false sharing)

__device__ __forceinline__ float bf2f(u16 v){ u32 u = ((u32)v) << 16; return __builtin_bit_cast(float, u); }
__device__ __forceinline__ u16 f2bf(float f){
  u32 u = __builtin_bit_cast(u32, f);
  u32 r = (u + 0x7FFFu + ((u >> 16) & 1u)) >> 16;   // round-nearest-even
  return (u16)r;
}
__device__ __forceinline__ float sigm(float x){
  return __builtin_amdgcn_rcpf(1.f + __builtin_amdgcn_exp2f(-1.4426950408889634f * x));
}
__device__ __forceinline__ float tanh_(float x){
  x = fminf(fmaxf(x, -30.f), 30.f);                 // avoid inf/inf
  float t = __builtin_amdgcn_exp2f(2.8853900817779268f * x);
  return (t - 1.f) * __builtin_amdgcn_rcpf(t + 1.f);
}

// global -> LDS async, 16B per lane. lds dest must be wave-uniform (HW adds lane*16).
__device__ __forceinline__ void gl2lds16(const void* g, void* s){
  __builtin_amdgcn_global_load_lds(
      (const __attribute__((address_space(1))) u32*)(uintptr_t)g,
      (__attribute__((address_space(3))) u32*)(u32)(uintptr_t)s, 16, 0, 0);
}

// ------------------------- prep: U fragment pack ---------------------------
// upack element e = layer<<19 | dir<<18 | g<<15 | w<<13 | kt<<9 | l<<3 | j
// rec lane l of wave w (= gate), WG g reads frag kt as 8 contiguous bf16.
__global__ void prep_upack(const float* __restrict__ U0f, const float* __restrict__ U0b,
                           const float* __restrict__ Uf,  const float* __restrict__ Ub,
                           u16* __restrict__ upack)
{
  int e = blockIdx.x * 256 + threadIdx.x;      // 0 .. 1572863
  int j     = e & 7;
  int l     = (e >> 3) & 63;
  int kt    = (e >> 9) & 15;
  int w     = (e >> 13) & 3;
  int g     = (e >> 15) & 7;
  int dir   = (e >> 18) & 1;
  int layer = e >> 19;
  int colg = w * 256 + g * 32 + (l & 31);       // gate*256 + unit
  int k    = kt * 16 + ((l >> 5) & 1) * 8 + j;  // K index (h unit)
  const float* src;
  if (layer == 0) src = dir ? U0b : U0f;
  else            src = (dir ? Ub : Uf) + (size_t)(layer - 1) * (U_ * H4_);
  upack[e] = f2bf(src[(size_t)k * H4_ + colg]);
}

// ------------------------- prep: W transpose -------------------------------
// wt[ld][colg][k] bf16, ld = (layer-1)*2 + dir ; dst index == e (coalesced writes)
__global__ void prep_wt(const float* __restrict__ Wf, const float* __restrict__ Wb,
                        u16* __restrict__ wt)
{
  int e = blockIdx.x * 256 + threadIdx.x;       // 0 .. 2097151
  int k    = e & 511;
  int colg = (e >> 9) & 1023;
  int ld   = e >> 19;                           // 0..3
  int layer = ld >> 1, dir = ld & 1;
  const float* src = (dir ? Wb : Wf) + (size_t)layer * (512 * H4_);
  wt[e] = f2bf(src[(size_t)k * H4_ + colg]);
}

__global__ void ws_fail(float* o){ o[0] = -1.0e6f; }

// ------------------------- xz GEMM (layers 1,2) ----------------------------
// xz[dir][sl][b][1024] = x_seq[t(dir,sl)][b][0:512] @ W + bias, bf16 out.
__global__ __launch_bounds__(256) void xz_gemm(
    const u16* __restrict__ xs,      // [T][32][512] bf16
    const u16* __restrict__ wt,      // [4][1024][512] bf16 (B^T panels)
    const float* __restrict__ bf_,   // [2][1024]
    const float* __restrict__ bb_,
    u16* __restrict__ xz,            // [2][CHUNK][32][1024] bf16
    int layer, int s0)
{
  const int bm = blockIdx.x;         // 64 M-tiles (8192 rows = 256 sl x 32 b)
  const int bn = blockIdx.y;         // 8 N-tiles
  const int dir = blockIdx.z;
  const int tid = threadIdx.x, w = tid >> 6, l = tid & 63;
  const int wm = w >> 1, wn = w & 1;
  __shared__ u16 As[128 * 64];
  __shared__ u16 Bs[128 * 64];
  const u16* wpanel = wt + (size_t)((layer - 1) * 2 + dir) * (H4_ * 512);
  const float* bias = (dir ? bb_ : bf_) + (size_t)(layer - 1) * H4_;
  f32x16 acc00{}, acc01{}, acc10{}, acc11{};

  for (int k0 = 0; k0 < 8; k0++){
    #pragma unroll
    for (int i = 0; i < 4; i++){               // stage A tile (128 rows x 64 k)
      int inst = i * 4 + w;
      int R = bm * 128 + inst * 8 + (l >> 3);
      int sl = R >> 5, b = R & 31;
      int t = dir ? (T_ - 1 - (s0 + sl)) : (s0 + sl);
      const u16* g = xs + ((size_t)(t * 32 + b) * 512 + k0 * 64 + (l & 7) * 8);
      gl2lds16(g, (void*)(As + inst * 512));
    }
    #pragma unroll
    for (int i = 0; i < 4; i++){               // stage B tile (128 cols x 64 k)
      int inst = i * 4 + w;
      int colg = bn * 128 + inst * 8 + (l >> 3);
      const u16* g = wpanel + ((size_t)colg * 512 + k0 * 64 + (l & 7) * 8);
      gl2lds16(g, (void*)(Bs + inst * 512));
    }
    asm volatile("s_waitcnt vmcnt(0)" ::: "memory");
    __syncthreads();
    #pragma unroll
    for (int kt = 0; kt < 4; kt++){
      int ko = kt * 16 + (l >> 5) * 8;
      short8 a0 = *(const short8*)(As + (wm * 64 +      (l & 31)) * 64 + ko);
      short8 a1 = *(const short8*)(As + (wm * 64 + 32 + (l & 31)) * 64 + ko);
      short8 b0 = *(const short8*)(Bs + (wn * 64 +      (l & 31)) * 64 + ko);
      short8 b1 = *(const short8*)(Bs + (wn * 64 + 32 + (l & 31)) * 64 + ko);
      acc00 = __builtin_amdgcn_mfma_f32_32x32x16_bf16(a0, b0, acc00, 0, 0, 0);
      acc01 = __builtin_amdgcn_mfma_f32_32x32x16_bf16(a0, b1, acc01, 0, 0, 0);
      acc10 = __builtin_amdgcn_mfma_f32_32x32x16_bf16(a1, b0, acc10, 0, 0, 0);
      acc11 = __builtin_amdgcn_mfma_f32_32x32x16_bf16(a1, b1, acc11, 0, 0, 0);
    }
    __syncthreads();
  }
  // epilogue: D layout col=l&31, row=(r&3)+8*(r>>2)+4*(l>>5)  [m74/m101]
  const int lrow = 4 * (l >> 5);
  auto epi = [&](const f32x16& A, int mi, int ni){
    int colg = bn * 128 + wn * 64 + ni * 32 + (l & 31);
    float bv = bias[colg];
    #pragma unroll
    for (int r = 0; r < 16; r++){
      int row = wm * 64 + mi * 32 + (r & 3) + 8 * (r >> 2) + lrow;
      int R = bm * 128 + row;
      int sl = R >> 5, b = R & 31;
      xz[((size_t)(dir * CHUNK + sl) * 32 + b) * 1024 + colg] = f2bf(A[r] + bv);
    }
  };
  epi(acc00, 0, 0); epi(acc01, 0, 1); epi(acc10, 1, 0); epi(acc11, 1, 1);
}

// ------------------------- recurrence --------------------------------------
// grid = 16 blocks (dir = bid>>3, slice g = bid&7), 256 threads (4 waves).
// Wave w computes gate w's 32 columns. Thread (b=tid&31, ug=tid>>5) owns
// units u0..u0+3 of the slice (c in registers).
// h_buf is fragment-ordered: F(b,u) = (u>>4)*512 + ((u>>3)&1)*256 + b*8 + (u&7)
// so staging is linear and ds_read_b128 A-frags are conflict-free.
__global__ __launch_bounds__(256) void rec_step(
    int layer, int s0, int nsteps,
    const float* __restrict__ x_in,   // layer0: [32][2048]
    const float* __restrict__ w0f, const float* __restrict__ w0b,
    const float* __restrict__ b0f, const float* __restrict__ b0b,
    const u16* __restrict__ upack,
    const u16* __restrict__ xz,       // [2][CHUNK][32][1024] (layers 1,2)
    u16*  __restrict__ xseq_out,      // layers 0,1 ([T][32][512] bf16)
    float* __restrict__ dout,         // layer 2
    u16*  __restrict__ h_buf,         // [2 dir][2 parity][8192] bf16
    float* __restrict__ state_c,      // [2 dir][8192] f32
    u32*  __restrict__ flags)         // [3][2][8*FLAG_STRIDE]
{
  const int bid = blockIdx.x;
  const int dir = bid >> 3, g = bid & 7;
  const int tid = threadIdx.x, w = tid >> 6, l = tid & 63;
  __shared__ u16 h_st[8192];             // 16KB, fragment order
  __shared__ float z_lds[32 * 132];      // [b][128 cols], padded stride

  // resident recurrent-weight B fragments
  short8 Bf[16];
  {
    const u16* up = upack + (size_t)((((layer * 2 + dir) * 8 + g) * 4 + w) * 16) * 512 + l * 8;
    #pragma unroll
    for (int kt = 0; kt < 16; kt++) Bf[kt] = *(const short8*)(up + kt * 512);
  }
  const int b = tid & 31, ug = tid >> 5;
  const int u0 = g * 32 + ug * 4;        // global unit base (0..255)
  float c[4];
  #pragma unroll
  for (int i = 0; i < 4; i++) c[i] = state_c[dir * 8192 + b * 256 + u0 + i];
  float w0v[4][4], bia[4][4];
  if (layer == 0){
    const float* W0 = dir ? w0b : w0f;
    const float* B0 = dir ? b0b : b0f;
    #pragma unroll
    for (int gt = 0; gt < 4; gt++)
      #pragma unroll
      for (int i = 0; i < 4; i++){
        w0v[gt][i] = W0[gt * 256 + u0 + i];
        bia[gt][i] = B0[gt * 256 + u0 + i];
      }
  }
  u16* hb  = h_buf + dir * 2 * 8192;
  u32* flg = flags + (layer * 2 + dir) * (8 * FLAG_STRIDE);

  for (int ss = 0; ss < nsteps; ss++){
    const int s = s0 + ss;
    const int t = dir ? (T_ - 1 - s) : s;

    // prefetch this step's input term (independent of flags -> hides latency)
    float xv = 0.f; uint2 xq0, xq1, xq2, xq3;
    if (layer == 0){
      xv = x_in[b * T_ + t];
    } else {
      const u16* xp = xz + ((size_t)(dir * CHUNK + ss) * 32 + b) * 1024 + u0;
      xq0 = *(const uint2*)(xp);
      xq1 = *(const uint2*)(xp + 256);
      xq2 = *(const uint2*)(xp + 512);
      xq3 = *(const uint2*)(xp + 768);
    }

    // wait until h_s fully published (flag g' >= s). s==0 passes trivially.
    if (w == 0 && l < 8){
      while (__hip_atomic_load(&flg[l * FLAG_STRIDE], __ATOMIC_ACQUIRE,
                               __HIP_MEMORY_SCOPE_AGENT) < (u32)s) {}
    }
    __syncthreads();

    // stage h_s (16KB, linear fragment order)
    {
      const u16* hsrc = hb + (s & 1) * 8192;
      #pragma unroll
      for (int i = 0; i < 4; i++){
        int inst = i * 4 + w;
        gl2lds16(hsrc + inst * 512 + l * 8, (void*)(h_st + inst * 512));
      }
    }
    asm volatile("s_waitcnt vmcnt(0)" ::: "memory");
    __syncthreads();

    // z(slice) = h_s @ U(slice)
    f32x16 acc{};
    #pragma unroll
    for (int kt = 0; kt < 16; kt++){
      short8 a = *(const short8*)(h_st + kt * 512 + l * 8);
      acc = __builtin_amdgcn_mfma_f32_32x32x16_bf16(a, Bf[kt], acc, 0, 0, 0);
    }
    {
      int cb = w * 32 + (l & 31);
      #pragma unroll
      for (int r = 0; r < 16; r++){
        int row = (r & 3) + 8 * (r >> 2) + 4 * (l >> 5);
        z_lds[row * 132 + cb] = acc[r];
      }
    }
    __syncthreads();

    // gates
    float hv[4];
    #pragma unroll
    for (int i = 0; i < 4; i++){
      float zi = z_lds[b * 132 +       ug * 4 + i];
      float zf = z_lds[b * 132 + 32  + ug * 4 + i];
      float zg = z_lds[b * 132 + 64  + ug * 4 + i];
      float zo = z_lds[b * 132 + 96  + ug * 4 + i];
      if (layer == 0){
        zi += xv * w0v[0][i] + bia[0][i];
        zf += xv * w0v[1][i] + bia[1][i];
        zg += xv * w0v[2][i] + bia[2][i];
        zo += xv * w0v[3][i] + bia[3][i];
      } else {
        zi += bf2f(((const u16*)&xq0)[i]);
        zf += bf2f(((const u16*)&xq1)[i]);
        zg += bf2f(((const u16*)&xq2)[i]);
        zo += bf2f(((const u16*)&xq3)[i]);
      }
      float si = sigm(zi), sf = sigm(zf), so = sigm(zo);
      c[i] = sf * c[i] + si * tanh_(zg);
      hv[i] = so * tanh_(c[i]);
    }

    // publish h_{s+1} (write-through to coherent point)
    u32 plo = (u32)f2bf(hv[0]) | ((u32)f2bf(hv[1]) << 16);
    u32 phi = (u32)f2bf(hv[2]) | ((u32)f2bf(hv[3]) << 16);
    {
      u64 hp = (u64)plo | ((u64)phi << 32);
      int F = (u0 >> 4) * 512 + ((u0 >> 3) & 1) * 256 + b * 8 + (u0 & 7);
      __hip_atomic_store((u64*)(hb + ((s + 1) & 1) * 8192 + F), hp,
                         __ATOMIC_RELAXED, __HIP_MEMORY_SCOPE_AGENT);
    }
    // sequence outputs
    if (layer < 2){
      *(uint2*)(xseq_out + (size_t)(t * 32 + b) * 512 + dir * 256 + u0) = make_uint2(plo, phi);
    } else {
      *(float4*)(dout + ((size_t)(b * T_ + t) * 512 + dir * 256 + u0)) =
          make_float4(hv[0], hv[1], hv[2], hv[3]);
    }
    if (ss == nsteps - 1){
      #pragma unroll
      for (int i = 0; i < 4; i++) state_c[dir * 8192 + b * 256 + u0 + i] = c[i];
      if (layer == 2 && s == T_ - 1){
        size_t sb = (size_t)B_ * T_ * 512;
        #pragma unroll
        for (int i = 0; i < 4; i++){
          dout[sb + (size_t)(dir * 2 + 0) * 8192 + b * 256 + u0 + i] = hv[i];  // hT
          dout[sb + (size_t)(dir * 2 + 1) * 8192 + b * 256 + u0 + i] = c[i];   // cT
        }
      }
    }
    // make h globally visible, then raise our flag
    asm volatile("s_waitcnt vmcnt(0)" ::: "memory");
    __syncthreads();
    if (tid == 0)
      __hip_atomic_store(&flg[g * FLAG_STRIDE], (u32)(s + 1),
                         __ATOMIC_RELAXED, __HIP_MEMORY_SCOPE_AGENT);
  }
}

// ------------------------- host --------------------------------------------
extern "C" void kernel_launch(void* const* d_in, const int* in_sizes, int n_in,
                              void* d_out, int out_size, void* d_ws, size_t ws_size,
                              hipStream_t stream)
{
  const float* x   = (const float*)d_in[0];
  const float* W0f = (const float*)d_in[1];
  const float* U0f = (const float*)d_in[2];
  const float* b0f = (const float*)d_in[3];
  const float* W0b = (const float*)d_in[4];
  const float* U0b = (const float*)d_in[5];
  const float* b0b = (const float*)d_in[6];
  const float* Wf  = (const float*)d_in[7];
  const float* Uf  = (const float*)d_in[8];
  const float* bf_ = (const float*)d_in[9];
  const float* Wb  = (const float*)d_in[10];
  const float* Ub  = (const float*)d_in[11];
  const float* bb_ = (const float*)d_in[12];
  float* out = (float*)d_out;

  char* base = (char*)d_ws;
  size_t off = 0;
  auto carve = [&](size_t bytes) -> char* {
    char* r = base + off;
    off += (bytes + 255) & ~(size_t)255;
    return r;
  };
  u16* xs0   = (u16*)carve((size_t)T_ * 32 * 512 * 2);        // 64MB
  u16* xs1   = (u16*)carve((size_t)T_ * 32 * 512 * 2);        // 64MB
  u16* xzbuf = (u16*)carve((size_t)2 * CHUNK * 32 * 1024 * 2);// 32MB
  u16* upack = (u16*)carve((size_t)1572864 * 2);              // 3MB
  u16* wt    = (u16*)carve((size_t)2097152 * 2);              // 4MB
  u16* hbuf  = (u16*)carve((size_t)2 * 2 * 8192 * 2);         // 64KB
  float* stc = (float*)carve((size_t)2 * 8192 * 4);           // 64KB
  u32* flags = (u32*)carve((size_t)3 * 2 * 8 * FLAG_STRIDE * 4);
  if (off > ws_size){
    ws_fail<<<1, 1, 0, stream>>>(out);   // sentinel: distinguishes ws-overflow
    return;
  }
  // zero h_buf (initial h=0), state_c (c=0), flags — every call (ws re-poisoned)
  size_t zbytes = (size_t)((char*)(flags + 3 * 2 * 8 * FLAG_STRIDE) - (char*)hbuf);
  hipMemsetAsync(hbuf, 0, zbytes, stream);

  prep_upack<<<6144, 256, 0, stream>>>(U0f, U0b, Uf, Ub, upack);
  prep_wt<<<8192, 256, 0, stream>>>(Wf, Wb, wt);

  // layer 0 (F=1 fused into gates), single launch over all 2048 steps
  rec_step<<<16, 256, 0, stream>>>(0, 0, T_, x, W0f, W0b, b0f, b0b,
                                   upack, nullptr, xs0, nullptr, hbuf, stc, flags);
  // layers 1,2: chunked GEMM + recurrence
  for (int layer = 1; layer <= 2; layer++){
    const u16* xsrc = (layer == 1) ? xs0 : xs1;
    u16* xdst = (layer == 1) ? xs1 : nullptr;
    for (int pch = 0; pch < T_ / CHUNK; pch++){
      xz_gemm<<<dim3(CHUNK * 32 / 128, H4_ / 128, 2), 256, 0, stream>>>(
          xsrc, wt, bf_, bb_, xzbuf, layer, pch * CHUNK);
      rec_step<<<16, 256, 0, stream>>>(layer, pch * CHUNK, CHUNK,
                                       nullptr, nullptr, nullptr, nullptr, nullptr,
                                       upack, xzbuf, xdst,
                                       (layer == 2) ? out : nullptr,
                                       hbuf, stc, flags);
    }
  }
}